// Round 1
// baseline (1352.044 us; speedup 1.0000x reference)
//
#include <hip/hip_runtime.h>
#include <math.h>

#define B_  64
#define T_  32
#define E_  512
#define D_  512
#define V_  32000
#define NT  31            // T-1 decode steps
#define G4  2048          // 4*D

__device__ __forceinline__ float sigmoidf_(float x) { return 1.f / (1.f + expf(-x)); }

// ---------------- kernel 1: stable descending argsort + init ----------------
__global__ void k_sort(const int* __restrict__ caplen, float* __restrict__ out_sind,
                       int* __restrict__ sind, int* __restrict__ declen,
                       int* __restrict__ Mact, int* __restrict__ rowlist,
                       float* __restrict__ h0, float* __restrict__ c0) {
    __shared__ int s_len[B_];
    __shared__ int s_dl[B_];
    int tid = threadIdx.x;
    if (tid < B_) s_len[tid] = caplen[tid];
    __syncthreads();
    if (tid < B_) {
        int len = s_len[tid];
        int rank = 0;
        for (int j = 0; j < B_; ++j) {
            int lj = s_len[j];
            rank += (lj > len) || (lj == len && j < tid);   // stable: ties by index
        }
        sind[rank] = tid;
        declen[rank] = len - 1;
        s_dl[rank] = len - 1;
        out_sind[rank] = (float)tid;
    }
    __syncthreads();
    if (tid == 0) {
        // active rows form a prefix in b for each t (dec_len sorted descending)
        int base = 0;
        for (int t = 0; t < NT; ++t) {
            int n = 0;
            for (int b = 0; b < B_; ++b) n += (t < s_dl[b]);
            for (int b = 0; b < n; ++b) rowlist[base + b] = t * B_ + b;
            base += n;
        }
        Mact[0] = base;
    }
    // zero-init h0/c0 (ws is re-poisoned 0xAA before every call)
    for (int i = tid; i < B_ * D_; i += blockDim.x) { h0[i] = 0.f; c0[i] = 0.f; }
}

// ---------------- kernel 2: zero-fill predictions ----------------
__global__ void k_zero(float4* __restrict__ out, int n4) {
    int i = blockIdx.x * blockDim.x + threadIdx.x;
    int stride = gridDim.x * blockDim.x;
    float4 z = make_float4(0.f, 0.f, 0.f, 0.f);
    for (; i < n4; i += stride) out[i] = z;
}

// ---------------- kernel 3: X = enc_sorted @ W_ih.T + b_ih + b_hh ----------------
// M=1984 (t-major: row = t*64+b), N=2048, K=512. BM=BN=64, BK=16, 4x4/thread.
__global__ __launch_bounds__(256) void k_xgemm(
    const float* __restrict__ enc, const float* __restrict__ Wih,
    const float* __restrict__ bih, const float* __restrict__ bhh,
    const int* __restrict__ sind, float* __restrict__ X) {
    __shared__ __align__(16) float sA[16 * 68];
    __shared__ __align__(16) float sB[16 * 68];
    __shared__ int s_sind[B_];
    int tid = threadIdx.x;
    int mt = blockIdx.x;            // = t (tile covers b = 0..63)
    int n0 = blockIdx.y * 64;
    if (tid < B_) s_sind[tid] = sind[tid];
    __syncthreads();
    int la = tid >> 2;              // 0..63
    int lk = (tid & 3) << 2;        // 0,4,8,12
    int tx = tid & 15, ty = tid >> 4;
    const float* arow = enc + ((long)s_sind[la] * T_ + mt) * E_;
    const float* brow = Wih + (long)(n0 + la) * E_;
    float acc[4][4] = {};
    for (int k0 = 0; k0 < E_; k0 += 16) {
        float4 a4 = *(const float4*)(arow + k0 + lk);
        float4 b4 = *(const float4*)(brow + k0 + lk);
        sA[(lk + 0) * 68 + la] = a4.x; sA[(lk + 1) * 68 + la] = a4.y;
        sA[(lk + 2) * 68 + la] = a4.z; sA[(lk + 3) * 68 + la] = a4.w;
        sB[(lk + 0) * 68 + la] = b4.x; sB[(lk + 1) * 68 + la] = b4.y;
        sB[(lk + 2) * 68 + la] = b4.z; sB[(lk + 3) * 68 + la] = b4.w;
        __syncthreads();
        #pragma unroll
        for (int kk = 0; kk < 16; ++kk) {
            float4 av = *(const float4*)&sA[kk * 68 + (ty << 2)];
            float4 bv = *(const float4*)&sB[kk * 68 + (tx << 2)];
            float a[4] = { av.x, av.y, av.z, av.w };
            float b[4] = { bv.x, bv.y, bv.z, bv.w };
            #pragma unroll
            for (int i = 0; i < 4; ++i)
                #pragma unroll
                for (int j = 0; j < 4; ++j)
                    acc[i][j] = fmaf(a[i], b[j], acc[i][j]);
        }
        __syncthreads();
    }
    #pragma unroll
    for (int i = 0; i < 4; ++i) {
        int b = (ty << 2) + i;
        int row = mt * 64 + b;
        int col0 = n0 + (tx << 2);
        float* xp = X + (long)row * G4 + col0;
        #pragma unroll
        for (int j = 0; j < 4; ++j)
            xp[j] = acc[i][j] + bih[col0 + j] + bhh[col0 + j];
    }
}

// ---------------- kernel 4: one LSTM step ----------------
// one wave per (b,d): 4 gate dot-products of length 512, butterfly reduce.
__global__ __launch_bounds__(256) void k_step(
    const float* __restrict__ X, const float* __restrict__ Whh,
    const float* __restrict__ h_old, const float* __restrict__ c_old,
    float* __restrict__ h_new, float* __restrict__ c_new,
    float* __restrict__ h_store, const int* __restrict__ declen, int t) {
    int gid = blockIdx.x * blockDim.x + threadIdx.x;
    int wid = gid >> 6;             // 0 .. 64*512-1
    int lane = threadIdx.x & 63;
    int b = wid >> 9;
    int d = wid & 511;
    const float* hrow = h_old + b * D_;
    float hk[8];
    #pragma unroll
    for (int j = 0; j < 8; ++j) hk[j] = hrow[lane + 64 * j];
    float acc[4];
    #pragma unroll
    for (int g = 0; g < 4; ++g) {
        const float* w = Whh + (long)(g * D_ + d) * D_;
        float a = 0.f;
        #pragma unroll
        for (int j = 0; j < 8; ++j) a = fmaf(hk[j], w[lane + 64 * j], a);
        acc[g] = a;
    }
    #pragma unroll
    for (int g = 0; g < 4; ++g)
        #pragma unroll
        for (int off = 32; off > 0; off >>= 1)
            acc[g] += __shfl_xor(acc[g], off, 64);
    if (lane == 0) {
        const float* xr = X + (long)(t * B_ + b) * G4 + d;
        float gi = sigmoidf_(xr[0]       + acc[0]);
        float gf = sigmoidf_(xr[D_]      + acc[1]);
        float gg = tanhf    (xr[2 * D_]  + acc[2]);
        float go = sigmoidf_(xr[3 * D_]  + acc[3]);
        float co = c_old[b * D_ + d];
        float cn = gf * co + gi * gg;
        float hn = go * tanhf(cn);
        h_store[(long)(t * B_ + b) * D_ + d] = hn;
        bool act = t < declen[b];
        float ho = h_old[b * D_ + d];
        h_new[b * D_ + d] = act ? hn : ho;
        c_new[b * D_ + d] = act ? cn : co;
    }
}

// ---------------- kernel 5: preds = h_store[active] @ fc_w.T + fc_b ----------------
// compact active rows, M<=1984, N=32000, K=512. Inactive rows stay zero-filled.
__global__ __launch_bounds__(256) void k_fc(
    const float* __restrict__ hstore, const float* __restrict__ fcw,
    const float* __restrict__ fcb, const int* __restrict__ rowlist,
    const int* __restrict__ Mact, float* __restrict__ out) {
    __shared__ __align__(16) float sA[16 * 68];
    __shared__ __align__(16) float sB[16 * 68];
    __shared__ int s_row[64];
    int tid = threadIdx.x;
    int mt = blockIdx.x;
    int n0 = blockIdx.y * 64;
    if (tid < 64) {
        int r = mt * 64 + tid;
        s_row[tid] = (r < Mact[0]) ? rowlist[r] : -1;
    }
    __syncthreads();
    if (s_row[0] < 0) return;       // whole tile beyond active rows
    int la = tid >> 2;
    int lk = (tid & 3) << 2;
    int tx = tid & 15, ty = tid >> 4;
    int rowA = s_row[la];
    bool avalid = rowA >= 0;
    const float* arow = hstore + (long)(avalid ? rowA : 0) * D_;
    const float* brow = fcw + (long)(n0 + la) * D_;
    float acc[4][4] = {};
    for (int k0 = 0; k0 < D_; k0 += 16) {
        float4 a4 = make_float4(0.f, 0.f, 0.f, 0.f);
        if (avalid) a4 = *(const float4*)(arow + k0 + lk);
        float4 b4 = *(const float4*)(brow + k0 + lk);
        sA[(lk + 0) * 68 + la] = a4.x; sA[(lk + 1) * 68 + la] = a4.y;
        sA[(lk + 2) * 68 + la] = a4.z; sA[(lk + 3) * 68 + la] = a4.w;
        sB[(lk + 0) * 68 + la] = b4.x; sB[(lk + 1) * 68 + la] = b4.y;
        sB[(lk + 2) * 68 + la] = b4.z; sB[(lk + 3) * 68 + la] = b4.w;
        __syncthreads();
        #pragma unroll
        for (int kk = 0; kk < 16; ++kk) {
            float4 av = *(const float4*)&sA[kk * 68 + (ty << 2)];
            float4 bv = *(const float4*)&sB[kk * 68 + (tx << 2)];
            float a[4] = { av.x, av.y, av.z, av.w };
            float b[4] = { bv.x, bv.y, bv.z, bv.w };
            #pragma unroll
            for (int i = 0; i < 4; ++i)
                #pragma unroll
                for (int j = 0; j < 4; ++j)
                    acc[i][j] = fmaf(a[i], b[j], acc[i][j]);
        }
        __syncthreads();
    }
    #pragma unroll
    for (int i = 0; i < 4; ++i) {
        int rv = s_row[(ty << 2) + i];
        if (rv < 0) continue;
        int tt = rv >> 6, b = rv & 63;
        int col0 = n0 + (tx << 2);
        float* op = out + ((long)(b * NT + tt)) * V_ + col0;
        float4 v = make_float4(acc[i][0] + fcb[col0 + 0], acc[i][1] + fcb[col0 + 1],
                               acc[i][2] + fcb[col0 + 2], acc[i][3] + fcb[col0 + 3]);
        *(float4*)op = v;
    }
}

extern "C" void kernel_launch(void* const* d_in, const int* in_sizes, int n_in,
                              void* d_out, int out_size, void* d_ws, size_t ws_size,
                              hipStream_t stream) {
    const float* enc    = (const float*)d_in[0];
    const int*   caplen = (const int*)d_in[1];
    const float* Wih    = (const float*)d_in[2];
    const float* Whh    = (const float*)d_in[3];
    const float* bih    = (const float*)d_in[4];
    const float* bhh    = (const float*)d_in[5];
    const float* fcw    = (const float*)d_in[6];
    const float* fcb    = (const float*)d_in[7];
    float* out = (float*)d_out;

    // workspace carve (floats): ~20.9 MB total
    float* ws = (float*)d_ws;
    int* sind    = (int*)ws;            // 64
    int* declen  = sind + 64;           // 64
    int* Mact    = declen + 64;         // 1 (padded to 64)
    int* rowlist = Mact + 64;           // up to 1984 (padded to 2048)
    float* h0     = (float*)(rowlist + 2048);   // offset 2240 floats (16B aligned)
    float* h1     = h0 + B_ * D_;
    float* c0     = h1 + B_ * D_;
    float* c1     = c0 + B_ * D_;
    float* hstore = c1 + B_ * D_;               // NT*B*D = 1,015,808 floats
    float* X      = hstore + (long)NT * B_ * D_; // NT*B*4D = 4,063,232 floats

    float* out_sind = out + (long)B_ * NT * V_; // predictions are 63,488,000 floats

    k_sort<<<1, 256, 0, stream>>>(caplen, out_sind, sind, declen, Mact, rowlist, h0, c0);
    k_zero<<<4096, 256, 0, stream>>>((float4*)out, (B_ * NT * V_) / 4);
    k_xgemm<<<dim3(NT, G4 / 64), 256, 0, stream>>>(enc, Wih, bih, bhh, sind, X);
    for (int t = 0; t < NT; ++t) {
        const float* ho = (t & 1) ? h1 : h0;
        const float* co = (t & 1) ? c1 : c0;
        float* hn = (t & 1) ? h0 : h1;
        float* cn = (t & 1) ? c0 : c1;
        k_step<<<8192, 256, 0, stream>>>(X, Whh, ho, co, hn, cn, hstore, declen, t);
    }
    k_fc<<<dim3(NT, V_ / 64), 256, 0, stream>>>(hstore, fcw, fcb, rowlist, Mact, out);
}

// Round 3
// 1175.635 us; speedup vs baseline: 1.1501x; 1.1501x over previous
//
#include <hip/hip_runtime.h>
#include <hip/hip_bf16.h>
#include <math.h>

#define B_  64
#define T_  32
#define E_  512
#define D_  512
#define V_  32000
#define NT  31            // T-1 decode steps
#define G4  2048          // 4*D

typedef __attribute__((ext_vector_type(8))) short short8;
typedef __attribute__((ext_vector_type(4))) float f32x4;
typedef __hip_bfloat16 bf16;

__device__ __forceinline__ float sigmoidf_(float x) { return 1.f / (1.f + expf(-x)); }
// gate-interleaved permutation: col n = d*4+gate  <->  original row gate*512+d
__device__ __forceinline__ int perm_(int n) { return ((n & 3) << 9) + (n >> 2); }

// ---------------- kernel 1: stable descending argsort + init ----------------
__global__ void k_sort(const int* __restrict__ caplen, float* __restrict__ out_sind,
                       int* __restrict__ sind, int* __restrict__ declen,
                       int* __restrict__ Mact, int* __restrict__ rowlist,
                       float* __restrict__ h0, float* __restrict__ c0) {
    __shared__ int s_len[B_];
    __shared__ int s_dl[B_];
    int tid = threadIdx.x;
    if (tid < B_) s_len[tid] = caplen[tid];
    __syncthreads();
    if (tid < B_) {
        int len = s_len[tid];
        int rank = 0;
        for (int j = 0; j < B_; ++j) {
            int lj = s_len[j];
            rank += (lj > len) || (lj == len && j < tid);   // stable: ties by index
        }
        sind[rank] = tid;
        declen[rank] = len - 1;
        s_dl[rank] = len - 1;
        out_sind[rank] = (float)tid;
    }
    __syncthreads();
    if (tid == 0) {
        int base = 0;
        for (int t = 0; t < NT; ++t) {
            int n = 0;
            for (int b = 0; b < B_; ++b) n += (t < s_dl[b]);
            for (int b = 0; b < n; ++b) rowlist[base + b] = t * B_ + b;
            base += n;
        }
        Mact[0] = base;
    }
    for (int i = tid; i < B_ * D_; i += blockDim.x) { h0[i] = 0.f; c0[i] = 0.f; }
}

// ---------------- kernel 2: zero-fill predictions ----------------
__global__ void k_zero(float4* __restrict__ out, int n4) {
    int i = blockIdx.x * blockDim.x + threadIdx.x;
    int stride = gridDim.x * blockDim.x;
    float4 z = make_float4(0.f, 0.f, 0.f, 0.f);
    for (; i < n4; i += stride) out[i] = z;
}

// ---------------- kernel 3: fc_w -> bf16 ----------------
__global__ void k_cvt_fcw(const float4* __restrict__ fcw, ushort4* __restrict__ fcwb, int n4) {
    int i = blockIdx.x * blockDim.x + threadIdx.x;
    int stride = gridDim.x * blockDim.x;
    for (; i < n4; i += stride) {
        float4 v = fcw[i];
        bf16 a = __float2bfloat16(v.x), b = __float2bfloat16(v.y);
        bf16 c = __float2bfloat16(v.z), d = __float2bfloat16(v.w);
        ushort4 o;
        o.x = *(unsigned short*)&a; o.y = *(unsigned short*)&b;
        o.z = *(unsigned short*)&c; o.w = *(unsigned short*)&d;
        fcwb[i] = o;
    }
}

// ---------------- kernel 4: X = enc_sorted @ Wih[perm].T + bias[perm] (fp32) ----------------
__global__ __launch_bounds__(256) void k_xgemm(
    const float* __restrict__ enc, const float* __restrict__ Wih,
    const float* __restrict__ bih, const float* __restrict__ bhh,
    const int* __restrict__ sind, float* __restrict__ X) {
    __shared__ __align__(16) float sA[16 * 68];
    __shared__ __align__(16) float sB[16 * 68];
    __shared__ int s_sind[B_];
    int tid = threadIdx.x;
    int mt = blockIdx.x;
    int n0 = blockIdx.y * 64;
    if (tid < B_) s_sind[tid] = sind[tid];
    __syncthreads();
    int la = tid >> 2;
    int lk = (tid & 3) << 2;
    int tx = tid & 15, ty = tid >> 4;
    const float* arow = enc + ((long)s_sind[la] * T_ + mt) * E_;
    const float* brow = Wih + (long)perm_(n0 + la) * E_;
    float acc[4][4] = {};
    for (int k0 = 0; k0 < E_; k0 += 16) {
        float4 a4 = *(const float4*)(arow + k0 + lk);
        float4 b4 = *(const float4*)(brow + k0 + lk);
        sA[(lk + 0) * 68 + la] = a4.x; sA[(lk + 1) * 68 + la] = a4.y;
        sA[(lk + 2) * 68 + la] = a4.z; sA[(lk + 3) * 68 + la] = a4.w;
        sB[(lk + 0) * 68 + la] = b4.x; sB[(lk + 1) * 68 + la] = b4.y;
        sB[(lk + 2) * 68 + la] = b4.z; sB[(lk + 3) * 68 + la] = b4.w;
        __syncthreads();
        #pragma unroll
        for (int kk = 0; kk < 16; ++kk) {
            float4 av = *(const float4*)&sA[kk * 68 + (ty << 2)];
            float4 bv = *(const float4*)&sB[kk * 68 + (tx << 2)];
            float a[4] = { av.x, av.y, av.z, av.w };
            float b[4] = { bv.x, bv.y, bv.z, bv.w };
            #pragma unroll
            for (int i = 0; i < 4; ++i)
                #pragma unroll
                for (int j = 0; j < 4; ++j)
                    acc[i][j] = fmaf(a[i], b[j], acc[i][j]);
        }
        __syncthreads();
    }
    #pragma unroll
    for (int i = 0; i < 4; ++i) {
        int b = (ty << 2) + i;
        int row = mt * 64 + b;
        int col0 = n0 + (tx << 2);
        float* xp = X + (long)row * G4 + col0;
        #pragma unroll
        for (int j = 0; j < 4; ++j) {
            int pc = perm_(col0 + j);
            xp[j] = acc[i][j] + bih[pc] + bhh[pc];
        }
    }
}

// ---------------- kernel 5: one LSTM step, exact fp32 ----------------
// grid 256 blocks x 256 thr. Block covers 8 gate-cols (= 2 d's x 4 gates), all 64 b.
// W slice staged in padded LDS; h streamed from global (L2-resident) as float4.
// Thread (tx=tid&7, ty=tid>>3): col n0+tx, rows 2ty, 2ty+1. 1024 FMA/thread.
__global__ __launch_bounds__(256) void k_step(
    const float* __restrict__ h_old, float* __restrict__ h_new,
    float* __restrict__ c, const float* __restrict__ X,
    const float* __restrict__ Whh, bf16* __restrict__ hstoreb,
    const int* __restrict__ declen, int t) {
    __shared__ __align__(16) float sW[8][520];   // padded: 520%32=8 -> tx spreads banks
    __shared__ float sg[8][65];
    __shared__ int sdl[B_];
    int tid = threadIdx.x;
    if (tid < B_) sdl[tid] = declen[tid];
    int n0 = blockIdx.x * 8;
    // stage W: 8 cols x 512 k, original Whh rows via perm (row-major, k contiguous)
    {
        int ci = tid >> 5;            // 0..7
        int kb = (tid & 31) << 4;     // 0,16,...,496
        const float* wr = Whh + (long)perm_(n0 + ci) * D_ + kb;
        float4 w0 = *(const float4*)(wr + 0);
        float4 w1 = *(const float4*)(wr + 4);
        float4 w2 = *(const float4*)(wr + 8);
        float4 w3 = *(const float4*)(wr + 12);
        *(float4*)&sW[ci][kb + 0]  = w0;
        *(float4*)&sW[ci][kb + 4]  = w1;
        *(float4*)&sW[ci][kb + 8]  = w2;
        *(float4*)&sW[ci][kb + 12] = w3;
    }
    __syncthreads();
    int tx = tid & 7;
    int ty = tid >> 3;                // 0..31
    int r0 = ty * 2, r1 = r0 + 1;
    const float* hA = h_old + r0 * D_;
    const float* hB = h_old + r1 * D_;
    float acc0 = 0.f, acc1 = 0.f;
    #pragma unroll 8
    for (int k = 0; k < D_; k += 4) {
        float4 w4 = *(const float4*)&sW[tx][k];
        float4 a4 = *(const float4*)(hA + k);
        float4 b4 = *(const float4*)(hB + k);
        acc0 = fmaf(a4.x, w4.x, acc0); acc0 = fmaf(a4.y, w4.y, acc0);
        acc0 = fmaf(a4.z, w4.z, acc0); acc0 = fmaf(a4.w, w4.w, acc0);
        acc1 = fmaf(b4.x, w4.x, acc1); acc1 = fmaf(b4.y, w4.y, acc1);
        acc1 = fmaf(b4.z, w4.z, acc1); acc1 = fmaf(b4.w, w4.w, acc1);
    }
    int n = n0 + tx;
    int g = tx & 3;
    float p0 = acc0 + X[(t * B_ + r0) * G4 + n];
    float p1 = acc1 + X[(t * B_ + r1) * G4 + n];
    sg[tx][r0] = (g == 2) ? tanhf(p0) : sigmoidf_(p0);
    sg[tx][r1] = (g == 2) ? tanhf(p1) : sigmoidf_(p1);
    __syncthreads();
    if (tid < 128) {
        int b = tid & 63, dl = tid >> 6;        // dl in {0,1}
        float gi = sg[dl * 4 + 0][b];
        float gf = sg[dl * 4 + 1][b];
        float gg = sg[dl * 4 + 2][b];
        float go = sg[dl * 4 + 3][b];
        int d = blockIdx.x * 2 + dl;
        int idx = b * D_ + d;
        float co = c[idx];
        float cn = gf * co + gi * gg;
        float hn = go * tanhf(cn);
        hstoreb[(t * B_ + b) * D_ + d] = __float2bfloat16(hn);
        if (t < sdl[b]) {
            c[idx] = cn;
            h_new[idx] = hn;
        } else {
            h_new[idx] = h_old[idx];
        }
    }
}

// ---------------- kernel 6: preds = hstore_b[active] @ fcw_b.T + fc_b (MFMA bf16) ----------------
__global__ __launch_bounds__(256) void k_fc(
    const bf16* __restrict__ hstoreb, const bf16* __restrict__ fcwb,
    const float* __restrict__ fcb, const int* __restrict__ rowlist,
    const int* __restrict__ Mact, float* __restrict__ out) {
    __shared__ int srow[128];
    int tid = threadIdx.x, lane = tid & 63, w = tid >> 6;
    int mt = blockIdx.x, nb = blockIdx.y;
    int Ma = Mact[0];
    if (mt * 128 >= Ma) return;           // uniform early-exit (zero-fill already done)
    if (tid < 128) {
        int r = mt * 128 + tid;
        srow[tid] = (r < Ma) ? rowlist[r] : -1;
    }
    __syncthreads();
    int m0w = (w & 1) * 64;
    int n0w = (w >> 1) * 64;
    int koff = (lane >> 4) << 3;
    const bf16* aptr[4];
    const bf16* bptr[4];
    #pragma unroll
    for (int ms = 0; ms < 4; ++ms) {
        int rv = srow[m0w + ms * 16 + (lane & 15)];
        aptr[ms] = hstoreb + (long)(rv < 0 ? 0 : rv) * D_ + koff;
    }
    #pragma unroll
    for (int ns = 0; ns < 4; ++ns) {
        int n = nb * 128 + n0w + ns * 16 + (lane & 15);
        bptr[ns] = fcwb + (long)n * D_ + koff;
    }
    f32x4 acc[4][4] = {};
    for (int kc = 0; kc < D_; kc += 32) {
        short8 a[4], b[4];
        #pragma unroll
        for (int ms = 0; ms < 4; ++ms) a[ms] = *(const short8*)(aptr[ms] + kc);
        #pragma unroll
        for (int ns = 0; ns < 4; ++ns) b[ns] = *(const short8*)(bptr[ns] + kc);
        #pragma unroll
        for (int ms = 0; ms < 4; ++ms)
            #pragma unroll
            for (int ns = 0; ns < 4; ++ns)
                acc[ms][ns] = __builtin_amdgcn_mfma_f32_16x16x32_bf16(a[ms], b[ns], acc[ms][ns], 0, 0, 0);
    }
    #pragma unroll
    for (int ms = 0; ms < 4; ++ms) {
        #pragma unroll
        for (int r = 0; r < 4; ++r) {
            int rloc = m0w + ms * 16 + ((lane >> 4) << 2) + r;
            int rv = srow[rloc];
            if (rv < 0) continue;
            int tt = rv >> 6, b = rv & 63;
            #pragma unroll
            for (int ns = 0; ns < 4; ++ns) {
                int n = nb * 128 + n0w + ns * 16 + (lane & 15);
                out[((long)(b * NT + tt)) * V_ + n] = acc[ms][ns][r] + fcb[n];
            }
        }
    }
}

extern "C" void kernel_launch(void* const* d_in, const int* in_sizes, int n_in,
                              void* d_out, int out_size, void* d_ws, size_t ws_size,
                              hipStream_t stream) {
    const float* enc    = (const float*)d_in[0];
    const int*   caplen = (const int*)d_in[1];
    const float* Wih    = (const float*)d_in[2];
    const float* Whh    = (const float*)d_in[3];
    const float* bih    = (const float*)d_in[4];
    const float* bhh    = (const float*)d_in[5];
    const float* fcw    = (const float*)d_in[6];
    const float* fcb    = (const float*)d_in[7];
    float* out = (float*)d_out;

    // workspace carve (~51.5 MB)
    char* ws = (char*)d_ws;
    int* sind    = (int*)ws;                          // 64
    int* declen  = sind + 64;                         // 64
    int* Mact    = declen + 64;                       // 64 (padded)
    int* rowlist = Mact + 64;                         // 2048
    char* p = (char*)(rowlist + 2048);
    p = (char*)(((size_t)p + 255) & ~(size_t)255);
    float* X      = (float*)p;            p += (size_t)NT * B_ * G4 * 4;   // 16.25 MB
    float* c      = (float*)p;            p += (size_t)B_ * D_ * 4;        // 128 KB
    float* h0     = (float*)p;            p += (size_t)B_ * D_ * 4;
    float* h1     = (float*)p;            p += (size_t)B_ * D_ * 4;
    bf16* hstoreb = (bf16*)p;             p += (size_t)NT * B_ * D_ * 2;   // 2 MB
    bf16* fcwb    = (bf16*)p;             p += (size_t)V_ * D_ * 2;        // 32.8 MB

    float* out_sind = out + (long)B_ * NT * V_;

    k_sort<<<1, 256, 0, stream>>>(caplen, out_sind, sind, declen, Mact, rowlist, h0, c);
    k_zero<<<4096, 256, 0, stream>>>((float4*)out, (B_ * NT * V_) / 4);
    k_cvt_fcw<<<4096, 256, 0, stream>>>((const float4*)fcw, (ushort4*)fcwb, (V_ * D_) / 4);
    k_xgemm<<<dim3(NT, G4 / 64), 256, 0, stream>>>(enc, Wih, bih, bhh, sind, X);
    for (int t = 0; t < NT; ++t) {
        const float* ho = (t & 1) ? h1 : h0;
        float* hn = (t & 1) ? h0 : h1;
        k_step<<<G4 / 8, 256, 0, stream>>>(ho, hn, c, X, Whh, hstoreb, declen, t);
    }
    k_fc<<<dim3(16, V_ / 128), 256, 0, stream>>>(hstoreb, fcwb, fcb, rowlist, Mact, out);
}